// Round 4
// baseline (4205.450 us; speedup 1.0000x reference)
//
// LSTM Seq2Seq persistent kernel, round 4: barrier-free tag-pair exchange +
// k-split MFMA waves.
//
//  - 256 WGs x 256 thr, 1 WG/CU (LDS ~90KB keeps it; >80KB forces 1/CU).
//    16 batch groups x 16 WGs; WG owns 64 fm cols: gcol = n*256 + 16*jm + c.
//  - h exchange: (value,tag) 8B pairs, single dwordx2 sc0/sc1 store (atomic
//    at 8B, no drain / no atomics / no barrier). Consumers poll pairs until
//    tag==step+1. Double buffer bounds skew; memset per launch clears tags.
//  - MFMA k-split: wave w owns k-tiles {w, w+4, w+8} for ALL 64 cols.
//    B-frags (hi/lo f16) in VGPRs (96). A-frag LDS reads: 6 b128/wave.
//    Partials reduced via fm_p[4][64][20] (padded, ~2-way banks).
//  - A staging: thread row=tid&15 (varies in quarter-wave) -> ~2-way writes.
//  - fp16 hi/lo split on A and B: fm = Ah*Bh + Ah*Bl + Al*Bh (fp32-grade).
//  - Decoder: 2 h-tiles/wave fm; z/LN/relu/y head with W1/W2 in LDS;
//    z exchanged via tag pairs too (tag = s+1, single buffer).

#include <hip/hip_runtime.h>
#include <cmath>

typedef _Float16 f16;
typedef _Float16 f16x8v __attribute__((ext_vector_type(8)));
typedef float f32x4v __attribute__((ext_vector_type(4)));
typedef unsigned long long u64;

#define NTHR 256

__device__ __forceinline__ float sigmoidf_(float x) { return 1.0f / (1.0f + expf(-x)); }

// (value, tag) pair publish: single 8B store, coherent at L3. No drain needed:
// each pair is self-validating for its consumer.
__device__ __forceinline__ void store_pair(u64* p, float v, unsigned tag) {
  u64 u = (u64)__float_as_uint(v) | ((u64)tag << 32);
  asm volatile("global_store_dwordx2 %0, %1, off sc0 sc1" :: "v"(p), "v"(u) : "memory");
}

// 8 consecutive dwordx4 (128B) coherent loads + single drain.
__device__ __forceinline__ void ld8_sc(const u64* p,
    float4& c0, float4& c1, float4& c2, float4& c3,
    float4& c4, float4& c5, float4& c6, float4& c7) {
  asm volatile(
      "global_load_dwordx4 %0, %8, off sc0 sc1\n\t"
      "global_load_dwordx4 %1, %8, off offset:16 sc0 sc1\n\t"
      "global_load_dwordx4 %2, %8, off offset:32 sc0 sc1\n\t"
      "global_load_dwordx4 %3, %8, off offset:48 sc0 sc1\n\t"
      "global_load_dwordx4 %4, %8, off offset:64 sc0 sc1\n\t"
      "global_load_dwordx4 %5, %8, off offset:80 sc0 sc1\n\t"
      "global_load_dwordx4 %6, %8, off offset:96 sc0 sc1\n\t"
      "global_load_dwordx4 %7, %8, off offset:112 sc0 sc1\n\t"
      "s_waitcnt vmcnt(0)"
      : "=&v"(c0), "=&v"(c1), "=&v"(c2), "=&v"(c3),
        "=&v"(c4), "=&v"(c5), "=&v"(c6), "=&v"(c7)
      : "v"(p)
      : "memory");
}

// Poll 16 pairs (128B) until every tag == want; emit the 16 values.
__device__ __forceinline__ void poll16(const u64* p, unsigned want, float* out) {
  float4 c0, c1, c2, c3, c4, c5, c6, c7;
  unsigned guard = 0;
  for (;;) {
    ld8_sc(p, c0, c1, c2, c3, c4, c5, c6, c7);
    bool ok = (__float_as_uint(c0.y) == want) && (__float_as_uint(c0.w) == want)
           && (__float_as_uint(c1.y) == want) && (__float_as_uint(c1.w) == want)
           && (__float_as_uint(c2.y) == want) && (__float_as_uint(c2.w) == want)
           && (__float_as_uint(c3.y) == want) && (__float_as_uint(c3.w) == want)
           && (__float_as_uint(c4.y) == want) && (__float_as_uint(c4.w) == want)
           && (__float_as_uint(c5.y) == want) && (__float_as_uint(c5.w) == want)
           && (__float_as_uint(c6.y) == want) && (__float_as_uint(c6.w) == want)
           && (__float_as_uint(c7.y) == want) && (__float_as_uint(c7.w) == want);
    if (ok) break;
    if (++guard > (1u << 22)) break;   // safety valve (wrong data -> absmax catches)
    __builtin_amdgcn_s_sleep(1);
  }
  out[0]  = c0.x; out[1]  = c0.z; out[2]  = c1.x; out[3]  = c1.z;
  out[4]  = c2.x; out[5]  = c2.z; out[6]  = c3.x; out[7]  = c3.z;
  out[8]  = c4.x; out[9]  = c4.z; out[10] = c5.x; out[11] = c5.z;
  out[12] = c6.x; out[13] = c6.z; out[14] = c7.x; out[15] = c7.z;
}

__device__ __forceinline__ void conv8_wr(float4 a, float4 b, f16* ph, f16* pl) {
  f16x8v h, l;
  h[0]=(f16)a.x; h[1]=(f16)a.y; h[2]=(f16)a.z; h[3]=(f16)a.w;
  h[4]=(f16)b.x; h[5]=(f16)b.y; h[6]=(f16)b.z; h[7]=(f16)b.w;
  l[0]=(f16)(a.x-(float)h[0]); l[1]=(f16)(a.y-(float)h[1]);
  l[2]=(f16)(a.z-(float)h[2]); l[3]=(f16)(a.w-(float)h[3]);
  l[4]=(f16)(b.x-(float)h[4]); l[5]=(f16)(b.y-(float)h[5]);
  l[6]=(f16)(b.z-(float)h[6]); l[7]=(f16)(b.w-(float)h[7]);
  *(f16x8v*)ph = h; *(f16x8v*)pl = l;
}

__device__ __forceinline__ void conv16_wr(const float* v, f16* ph, f16* pl) {
  f16x8v h0, h1, l0, l1;
  #pragma unroll
  for (int j = 0; j < 8; ++j) {
    h0[j] = (f16)v[j];     l0[j] = (f16)(v[j]     - (float)h0[j]);
    h1[j] = (f16)v[8 + j]; l1[j] = (f16)(v[8 + j] - (float)h1[j]);
  }
  *(f16x8v*)ph = h0; *(f16x8v*)(ph + 8) = h1;
  *(f16x8v*)pl = l0; *(f16x8v*)(pl + 8) = l1;
}

__global__ __launch_bounds__(NTHR, 1) void lstm_k(
    const float* __restrict__ X,  const float* __restrict__ Wx,
    const float* __restrict__ Wh, const float* __restrict__ Bg,
    const float* __restrict__ W1, const float* __restrict__ B1,
    const float* __restrict__ LNG, const float* __restrict__ LNB,
    const float* __restrict__ W2, const float* __restrict__ B2,
    float* __restrict__ Y, u64* __restrict__ HP, u64* __restrict__ ZP)
{
  // LDS ~90KB (forces 1 WG/CU)
  __shared__ f16   A_hi[16][392];     // cols 0..127 x(t), 128..383 h(t-1); 784B stride
  __shared__ f16   A_lo[16][392];
  __shared__ float fm_p[4][64][20];   // per-wave partials [w][col][row(16)+pad]
  __shared__ float hst[16][260];      // decoder f32 staging
  __shared__ float w1_lds[16][268];   // W1 slice transposed [col][k]
  __shared__ float w2_lds[8][268];    // W2 slice transposed [col][k]
  __shared__ float lng_lds[256], lnb_lds[256];
  __shared__ float ln_mu[16], ln_rs[16];

  const int tid = threadIdx.x;
  const int wg  = blockIdx.x;
  const int g   = wg & 15;
  const int jm  = wg >> 4;
  const int n0  = g * 16;
  const int k0  = jm * 16;

  const int l     = tid & 63;
  const int w     = __builtin_amdgcn_readfirstlane(tid >> 6);
  const int lr    = l & 15;           // frag row / local col
  const int krow0 = (l >> 4) * 8;     // k octet in 32-k tile

  const int srow = tid & 15;          // staging: row (varies within quarter-wave)
  const int scb  = tid >> 4;          // staging: col block

  // ---- B fragments in registers: wave w owns k-tiles {w, w+4, w+8} ----
  f16x8v Bh[3][4], Bl[3][4];
  #pragma unroll
  for (int ki = 0; ki < 3; ++ki) {
    const int kt = w + 4 * ki;
    #pragma unroll
    for (int n = 0; n < 4; ++n) {
      const int gcol = n * 256 + k0 + lr;
      #pragma unroll
      for (int j = 0; j < 8; ++j) {
        int k = kt * 32 + krow0 + j;
        float v = (k < 128) ? Wx[k * 1024 + gcol] : Wh[(k - 128) * 1024 + gcol];
        f16 hi = (f16)v;
        Bh[ki][n][j] = hi;
        Bl[ki][n][j] = (f16)(v - (float)hi);
      }
    }
  }

  // ---- head weights / LN params ----
  for (int idx = tid; idx < 256 * 16; idx += NTHR) {
    int k = idx >> 4, cc = idx & 15;
    w1_lds[cc][k] = W1[k * 256 + k0 + cc];
  }
  for (int idx = tid; idx < 256 * 8; idx += NTHR) {
    int k = idx >> 3, cc = idx & 7;
    w2_lds[cc][k] = W2[k * 128 + jm * 8 + cc];
  }
  lng_lds[tid] = LNG[tid];
  lnb_lds[tid] = LNB[tid];

  const int gr = tid >> 4, gk = tid & 15;
  const float bias0 = Bg[      k0 + gk];
  const float bias1 = Bg[256 + k0 + gk];
  const float bias2 = Bg[512 + k0 + gk];
  const float bias3 = Bg[768 + k0 + gk];
  const float b1reg = B1[k0 + gk];
  const float b2reg = (tid < 128) ? B2[jm * 8 + (tid & 7)] : 0.0f;
  float c_reg = 0.0f;

  // ---- prologue: zero h-region of A, stage x(0) ----
  {
    f16x8v z8 = {0, 0, 0, 0, 0, 0, 0, 0};
    *(f16x8v*)&A_hi[srow][128 + scb * 16]     = z8;
    *(f16x8v*)&A_hi[srow][128 + scb * 16 + 8] = z8;
    *(f16x8v*)&A_lo[srow][128 + scb * 16]     = z8;
    *(f16x8v*)&A_lo[srow][128 + scb * 16 + 8] = z8;
    const float* xp = X + (size_t)(n0 + srow) * 131072 + (size_t)scb * 8;
    float4 xa = *(const float4*)xp;
    float4 xb = *(const float4*)(xp + 4);
    conv8_wr(xa, xb, &A_hi[srow][scb * 8], &A_lo[srow][scb * 8]);
  }
  __syncthreads();

  // ================= ENCODER (t = 0..1023) =================
  for (int t = 0; t < 1024; ++t) {
    // A fragments: x-tile (kt=w) + h-tiles (kt=w+4, w+8)
    f16x8v axh = *(const f16x8v*)&A_hi[lr][w * 32 + krow0];
    f16x8v axl = *(const f16x8v*)&A_lo[lr][w * 32 + krow0];
    f16x8v ah1 = *(const f16x8v*)&A_hi[lr][128 + w * 32 + krow0];
    f16x8v al1 = *(const f16x8v*)&A_lo[lr][128 + w * 32 + krow0];
    f16x8v ah2 = *(const f16x8v*)&A_hi[lr][128 + (w + 4) * 32 + krow0];
    f16x8v al2 = *(const f16x8v*)&A_lo[lr][128 + (w + 4) * 32 + krow0];

    f32x4v ac0[4], ac1[4], ac2[4];
    #pragma unroll
    for (int n = 0; n < 4; ++n) { ac0[n] = {0,0,0,0}; ac1[n] = {0,0,0,0}; ac2[n] = {0,0,0,0}; }
    #pragma unroll
    for (int n = 0; n < 4; ++n) {
      ac0[n] = __builtin_amdgcn_mfma_f32_16x16x32_f16(axh, Bh[0][n], ac0[n], 0, 0, 0);
      ac1[n] = __builtin_amdgcn_mfma_f32_16x16x32_f16(axh, Bl[0][n], ac1[n], 0, 0, 0);
      ac2[n] = __builtin_amdgcn_mfma_f32_16x16x32_f16(axl, Bh[0][n], ac2[n], 0, 0, 0);
      ac0[n] = __builtin_amdgcn_mfma_f32_16x16x32_f16(ah1, Bh[1][n], ac0[n], 0, 0, 0);
      ac1[n] = __builtin_amdgcn_mfma_f32_16x16x32_f16(ah1, Bl[1][n], ac1[n], 0, 0, 0);
      ac2[n] = __builtin_amdgcn_mfma_f32_16x16x32_f16(al1, Bh[1][n], ac2[n], 0, 0, 0);
      ac0[n] = __builtin_amdgcn_mfma_f32_16x16x32_f16(ah2, Bh[2][n], ac0[n], 0, 0, 0);
      ac1[n] = __builtin_amdgcn_mfma_f32_16x16x32_f16(ah2, Bl[2][n], ac1[n], 0, 0, 0);
      ac2[n] = __builtin_amdgcn_mfma_f32_16x16x32_f16(al2, Bh[2][n], ac2[n], 0, 0, 0);
    }
    #pragma unroll
    for (int n = 0; n < 4; ++n) {
      f32x4v s = ac0[n] + ac1[n] + ac2[n];
      *(f32x4v*)&fm_p[w][n * 16 + lr][(l >> 4) * 4] = s;
    }
    __syncthreads();

    {  // gates: sum 4 wave-partials + bias, activations, publish h
      float fi = bias0, ff = bias1, fo = bias2, fg = bias3;
      #pragma unroll
      for (int ww = 0; ww < 4; ++ww) {
        fi += fm_p[ww][     gk][gr];
        ff += fm_p[ww][16 + gk][gr];
        fo += fm_p[ww][32 + gk][gr];
        fg += fm_p[ww][48 + gk][gr];
      }
      float si = sigmoidf_(fi), sf = sigmoidf_(ff), so = sigmoidf_(fo);
      float tg = tanhf(fg);
      c_reg = c_reg * sf + si * tg;
      float hv = so * tanhf(c_reg);
      store_pair(HP + (size_t)(t & 1) * 65536 + (size_t)(n0 + gr) * 256 + k0 + gk,
                 hv, (unsigned)(t + 1));
    }

    if (t < 1023) {
      // stage x(t+1) (plain cached loads; overlaps the poll below)
      const float* xp = X + (size_t)(n0 + srow) * 131072 + (size_t)(t + 1) * 128
                          + (size_t)scb * 8;
      float4 xa = *(const float4*)xp;
      float4 xb = *(const float4*)(xp + 4);
      conv8_wr(xa, xb, &A_hi[srow][scb * 8], &A_lo[srow][scb * 8]);
      // poll h(t) pairs, stage into A h-region
      float hv16[16];
      poll16(HP + (size_t)(t & 1) * 65536 + (size_t)(n0 + srow) * 256 + scb * 16,
             (unsigned)(t + 1), hv16);
      conv16_wr(hv16, &A_hi[srow][128 + scb * 16], &A_lo[srow][128 + scb * 16]);
    }
    __syncthreads();
  }

  // ---- decoder prologue: stage h(1023) into A ----
  {
    float hv16[16];
    poll16(HP + (size_t)65536 + (size_t)(n0 + srow) * 256 + scb * 16, 1024u, hv16);
    conv16_wr(hv16, &A_hi[srow][128 + scb * 16], &A_lo[srow][128 + scb * 16]);
  }
  __syncthreads();

  // ================= DECODER (s = 0..31) =================
  for (int s = 0; s < 32; ++s) {
    const int t = 1024 + s;

    // fm = h @ Wh + b : h-tiles only (kt = w+4, w+8)
    f16x8v ah1 = *(const f16x8v*)&A_hi[lr][128 + w * 32 + krow0];
    f16x8v al1 = *(const f16x8v*)&A_lo[lr][128 + w * 32 + krow0];
    f16x8v ah2 = *(const f16x8v*)&A_hi[lr][128 + (w + 4) * 32 + krow0];
    f16x8v al2 = *(const f16x8v*)&A_lo[lr][128 + (w + 4) * 32 + krow0];

    f32x4v ac0[4], ac1[4], ac2[4];
    #pragma unroll
    for (int n = 0; n < 4; ++n) { ac0[n] = {0,0,0,0}; ac1[n] = {0,0,0,0}; ac2[n] = {0,0,0,0}; }
    #pragma unroll
    for (int n = 0; n < 4; ++n) {
      ac0[n] = __builtin_amdgcn_mfma_f32_16x16x32_f16(ah1, Bh[1][n], ac0[n], 0, 0, 0);
      ac1[n] = __builtin_amdgcn_mfma_f32_16x16x32_f16(ah1, Bl[1][n], ac1[n], 0, 0, 0);
      ac2[n] = __builtin_amdgcn_mfma_f32_16x16x32_f16(al1, Bh[1][n], ac2[n], 0, 0, 0);
      ac0[n] = __builtin_amdgcn_mfma_f32_16x16x32_f16(ah2, Bh[2][n], ac0[n], 0, 0, 0);
      ac1[n] = __builtin_amdgcn_mfma_f32_16x16x32_f16(ah2, Bl[2][n], ac1[n], 0, 0, 0);
      ac2[n] = __builtin_amdgcn_mfma_f32_16x16x32_f16(al2, Bh[2][n], ac2[n], 0, 0, 0);
    }
    #pragma unroll
    for (int n = 0; n < 4; ++n) {
      f32x4v sum = ac0[n] + ac1[n] + ac2[n];
      *(f32x4v*)&fm_p[w][n * 16 + lr][(l >> 4) * 4] = sum;
    }
    __syncthreads();

    {  // RAW gates (reference decoder has no activations on i,f,o,g)
      float fi = bias0, ff = bias1, fo = bias2, fg = bias3;
      #pragma unroll
      for (int ww = 0; ww < 4; ++ww) {
        fi += fm_p[ww][     gk][gr];
        ff += fm_p[ww][16 + gk][gr];
        fo += fm_p[ww][32 + gk][gr];
        fg += fm_p[ww][48 + gk][gr];
      }
      c_reg = c_reg * ff + fi * fg;
      float hv = fo * tanhf(c_reg);
      store_pair(HP + (size_t)(t & 1) * 65536 + (size_t)(n0 + gr) * 256 + k0 + gk,
                 hv, (unsigned)(t + 1));
    }

    {  // poll h(t): stage into hst (f32) and A (f16 hi/lo)
      float hv16[16];
      poll16(HP + (size_t)(t & 1) * 65536 + (size_t)(n0 + srow) * 256 + scb * 16,
             (unsigned)(t + 1), hv16);
      conv16_wr(hv16, &A_hi[srow][128 + scb * 16], &A_lo[srow][128 + scb * 16]);
      #pragma unroll
      for (int j = 0; j < 4; ++j)
        *(float4*)&hst[srow][scb * 16 + 4 * j] = *(const float4*)&hv16[4 * j];
    }
    __syncthreads();

    {  // z = h @ W1 + b1, publish
      float za = b1reg;
      const float* hr = &hst[gr][0];
      const float* wr = &w1_lds[gk][0];
      #pragma unroll 4
      for (int kc = 0; kc < 64; ++kc) {
        float4 h4 = *(const float4*)(hr + kc * 4);
        float4 w4 = *(const float4*)(wr + kc * 4);
        za = fmaf(h4.x, w4.x, fmaf(h4.y, w4.y, fmaf(h4.z, w4.z, fmaf(h4.w, w4.w, za))));
      }
      store_pair(ZP + (size_t)(n0 + gr) * 256 + k0 + gk, za, (unsigned)(s + 1));
    }
    __syncthreads();   // all hst h-reads done before z overwrites it

    {  // poll z -> hst
      float hv16[16];
      poll16(ZP + (size_t)(n0 + srow) * 256 + scb * 16, (unsigned)(s + 1), hv16);
      #pragma unroll
      for (int j = 0; j < 4; ++j)
        *(float4*)&hst[srow][scb * 16 + 4 * j] = *(const float4*)&hv16[4 * j];
    }
    __syncthreads();

    {  // LayerNorm stats
      const float* zr = &hst[gr][0];
      float s1 = 0.f, s2 = 0.f;
      #pragma unroll
      for (int u = 0; u < 16; ++u) { float v = zr[gk * 16 + u]; s1 += v; s2 += v * v; }
      #pragma unroll
      for (int d = 1; d < 16; d <<= 1) { s1 += __shfl_xor(s1, d); s2 += __shfl_xor(s2, d); }
      float mu = s1 * (1.0f / 256.0f);
      float var = s2 * (1.0f / 256.0f) - mu * mu;
      float rstd = rsqrtf(var + 1e-5f);
      if (gk == 0) { ln_mu[gr] = mu; ln_rs[gr] = rstd; }
    }
    __syncthreads();

    #pragma unroll
    for (int rep = 0; rep < 4; ++rep) {  // normalize + affine + relu in place
      int f = tid + 256 * rep, r = f >> 6, kq = f & 63;
      float mu = ln_mu[r], rs = ln_rs[r];
      float4 v = *(float4*)&hst[r][kq * 4];
      int cb = kq * 4;
      v.x = fmaxf(fmaf((v.x - mu) * rs, lng_lds[cb    ], lnb_lds[cb    ]), 0.f);
      v.y = fmaxf(fmaf((v.y - mu) * rs, lng_lds[cb + 1], lnb_lds[cb + 1]), 0.f);
      v.z = fmaxf(fmaf((v.z - mu) * rs, lng_lds[cb + 2], lnb_lds[cb + 2]), 0.f);
      v.w = fmaxf(fmaf((v.w - mu) * rs, lng_lds[cb + 3], lnb_lds[cb + 3]), 0.f);
      *(float4*)&hst[r][kq * 4] = v;
    }
    __syncthreads();

    if (tid < 128) {  // y = relu(zn) @ W2 + b2
      int r = tid >> 3, yc = tid & 7;
      float ya = b2reg;
      const float* zr = &hst[r][0];
      const float* wr = &w2_lds[yc][0];
      #pragma unroll 4
      for (int kc = 0; kc < 64; ++kc) {
        float4 z4 = *(const float4*)(zr + kc * 4);
        float4 w4 = *(const float4*)(wr + kc * 4);
        ya = fmaf(z4.x, w4.x, fmaf(z4.y, w4.y, fmaf(z4.z, w4.z, fmaf(z4.w, w4.w, ya))));
      }
      Y[(size_t)(n0 + r) * 4096 + (size_t)s * 128 + jm * 8 + yc] = ya;
    }
  }
}

extern "C" void kernel_launch(void* const* d_in, const int* in_sizes, int n_in,
                              void* d_out, int out_size, void* d_ws, size_t ws_size,
                              hipStream_t stream) {
  const float* X   = (const float*)d_in[0];
  const float* Wx  = (const float*)d_in[1];
  const float* Wh  = (const float*)d_in[2];
  const float* b   = (const float*)d_in[3];
  const float* W1  = (const float*)d_in[4];
  const float* b1  = (const float*)d_in[5];
  const float* lng = (const float*)d_in[6];
  const float* lnb = (const float*)d_in[7];
  const float* W2  = (const float*)d_in[8];
  const float* b2  = (const float*)d_in[9];
  float* Y = (float*)d_out;

  // ws: HP = h pair double buffer [2][256][256] u64 (1MB); ZP = z pairs (512KB)
  u64* HP = (u64*)d_ws;
  u64* ZP = HP + 2 * 65536;
  (void)in_sizes; (void)n_in; (void)out_size; (void)ws_size;

  // clear tags each launch (graph-replay safe: stream-ordered)
  hipMemsetAsync(d_ws, 0, 3 * 65536 * sizeof(u64), stream);
  hipLaunchKernelGGL(lstm_k, dim3(256), dim3(NTHR), 0, stream,
                     X, Wx, Wh, b, W1, b1, lng, lnb, W2, b2, Y, HP, ZP);
}